// Round 6
// baseline (547.032 us; speedup 1.0000x reference)
//
#include <hip/hip_runtime.h>

// GNN layer: messages = relu(NF @ Wm^T + bm); agg = (adj @ messages)/deg; GRU(agg, NF)
// N=8192, D=128.
// v6 structure: the 268-MB adj read is decoupled from the GEMM.
//  k0: adj(int32) -> bits (8 MB, 1 bit/entry, ballot-packed) + per-row degree.
//      Pure stream, saturates HBM (~45 us) -- the GEMM-coupled versions (R3-R5)
//      were all pinned at ~133 us regardless of pipeline structure.
//  k2: A-frags unpacked from L2-resident bits (uint4 per lane per 2 steps);
//      B via R4's verified async-DMA XOR-swizzle LDS double buffer.
//  k3: GRU, degree straight from k0.

#define NN 8192
#define DIM 128
#define LSTR 136     // k1/k3 LDS row stride (shorts)
#define KSPLIT 4
#define NSTEP 32     // (8192/KSPLIT)/64 steps of K=64

typedef __bf16 bf16x8 __attribute__((ext_vector_type(8)));
typedef float f32x4 __attribute__((ext_vector_type(4)));

__device__ __forceinline__ unsigned short f2bf(float f) {
  union { float f; unsigned u; } v; v.f = f;
  unsigned r = v.u + 0x7FFF + ((v.u >> 16) & 1);  // RNE
  return (unsigned short)(r >> 16);
}
__device__ __forceinline__ float sigmoidf_(float x) {
  return 1.0f / (1.0f + __expf(-x));
}
__device__ __forceinline__ float tanhf_(float x) {
  float e = __expf(-2.0f * fabsf(x));
  float r = (1.0f - e) / (1.0f + e);
  return x < 0.0f ? -r : r;
}
__device__ __forceinline__ void pack4(float4 v, unsigned short* dst) {
  dst[0] = f2bf(v.x); dst[1] = f2bf(v.y); dst[2] = f2bf(v.z); dst[3] = f2bf(v.w);
}
// async 16B/lane global->LDS DMA; lds dest wave-uniform (HW adds lane*16)
__device__ __forceinline__ void async16(const void* g, void* l) {
  __builtin_amdgcn_global_load_lds(
      (const __attribute__((address_space(1))) unsigned int*)g,
      (__attribute__((address_space(3))) unsigned int*)l, 16, 0, 0);
}

// ---------------- K0: adj -> bitmask + degree. bits[row][w] bit j = adj[row][w*32+j]!=0
__global__ __launch_bounds__(256) void k0_pack(
    const int* __restrict__ adj, unsigned int* __restrict__ bits,
    int* __restrict__ deg) {
  const int t = threadIdx.x;
  const int lane = t & 63, wave = t >> 6;
  const int wid = blockIdx.x * 4 + wave;       // 0..4095, 2 rows each
#pragma unroll
  for (int rr = 0; rr < 2; ++rr) {
    const int row = wid * 2 + rr;
    const int* src = adj + (size_t)row * NN + lane;
    int dsum = 0;
#pragma unroll 8
    for (int i = 0; i < 128; ++i) {            // 64 ints per round, coalesced
      const int v = src[i * 64];
      const unsigned long long b = __ballot(v != 0);
      dsum += __popcll(b);
      if (lane == 0)
        *(uint2*)(bits + (size_t)row * 256 + i * 2) =
            make_uint2((unsigned)b, (unsigned)(b >> 32));
    }
    if (lane == 0) deg[row] = dsum;
  }
}

// ---------------- K1: msgT[o][m] = relu(NF @ Wm^T + bm) bf16, coalesced stores
__global__ __launch_bounds__(256) void k1_msg(
    const float* __restrict__ nf, const float* __restrict__ w_msg,
    const float* __restrict__ b_msg, unsigned short* __restrict__ msgT) {
  __shared__ unsigned short wm[128 * LSTR];   // wm[o][k]; reused as T[o][m] (stride 72)
  __shared__ unsigned short nfl[64 * LSTR];
  const int t = threadIdx.x;
  const int m0 = blockIdx.x * 64;
  const float4* wm4 = (const float4*)w_msg;
  const float4* nf4 = (const float4*)nf;
  for (int i = t; i < 4096; i += 256)
    pack4(wm4[i], &wm[(i >> 5) * LSTR + (i & 31) * 4]);
  for (int i = t; i < 2048; i += 256)
    pack4(nf4[m0 * 32 + i], &nfl[(i >> 5) * LSTR + (i & 31) * 4]);
  __syncthreads();
  const int lane = t & 63, wave = t >> 6;
  const int quad = lane >> 4, l16 = lane & 15;
  const int rt = wave;
  f32x4 acc[8];
  for (int j = 0; j < 8; ++j) acc[j] = (f32x4){0.f, 0.f, 0.f, 0.f};
  for (int kk = 0; kk < 4; ++kk) {
    bf16x8 a = *(const bf16x8*)&nfl[(rt * 16 + l16) * LSTR + kk * 32 + quad * 8];
    for (int ct = 0; ct < 8; ++ct) {
      bf16x8 b = *(const bf16x8*)&wm[(ct * 16 + l16) * LSTR + kk * 32 + quad * 8];
      acc[ct] = __builtin_amdgcn_mfma_f32_16x16x32_bf16(a, b, acc[ct], 0, 0, 0);
    }
  }
  __syncthreads();
  for (int ct = 0; ct < 8; ++ct) {
    const int o = ct * 16 + l16;
    const float bias = b_msg[o];
    for (int r = 0; r < 4; ++r)
      wm[o * 72 + rt * 16 + quad * 4 + r] = f2bf(fmaxf(acc[ct][r] + bias, 0.0f));
  }
  __syncthreads();
  for (int i = t; i < 1024; i += 256) {
    const int o = i >> 3, seg = i & 7;
    *(int4*)&msgT[o * NN + m0 + seg * 8] = *(const int4*)&wm[o * 72 + seg * 8];
  }
}

// ---------------- K2 v6: A from bits (L2), B via DMA double-buffered LDS
__global__ __launch_bounds__(256, 4) void k2_agg(
    const unsigned int* __restrict__ bits, const unsigned short* __restrict__ msgT,
    float* __restrict__ part) {
  __shared__ unsigned short bT[2][128 * 64];  // [o][XOR-swizzled 16B chunks], 16 KB/buf
  const int t = threadIdx.x;
  const int lane = t & 63, wave = t >> 6;
  const int quad = lane >> 4, l16 = lane & 15;
  const int sw = l16 & 7;
  const int mt = blockIdx.x >> 2, split = blockIdx.x & 3;
  const int m0 = mt * 64, kb = split * (NN / KSPLIT);

  // B staging descriptors (4 DMA issues/wave/step, R4-verified mechanics)
  const unsigned short* bSrc[4];
  int bLds[4];
#pragma unroll
  for (int j = 0; j < 4; ++j) {
    const int seg = wave * 4 + j;                 // 0..15
    const int ob = seg * 8 + (lane >> 3);         // B row o 0..127
    const int cbk = (lane & 7) ^ (ob & 7);        // logical 16B chunk (8 shorts)
    bSrc[j] = msgT + (size_t)ob * NN + kb + cbk * 8;
    bLds[j] = seg * 1024;
  }
  // A bits: one uint4 per lane per 2 steps (quads duplicate row's dwords)
  const int rowA = m0 + wave * 16 + l16;
  const uint4* bitsRow = (const uint4*)(bits + (size_t)rowA * 256 + split * 64);

  f32x4 acc[8];
#pragma unroll
  for (int j = 0; j < 8; ++j) acc[j] = (f32x4){0.f, 0.f, 0.f, 0.f};

  // prologue: stage step 0 into buf 0; prefetch bits for steps 0-1
#pragma unroll
  for (int j = 0; j < 4; ++j) async16(bSrc[j], (char*)&bT[0][0] + bLds[j]);
  uint4 bw = bitsRow[0], bwn;

  for (int s = 0; s < NSTEP; ++s) {
    const int buf = s & 1;
    __syncthreads();  // buf's DMA landed (vmcnt0 drain, ~L2 latency); buf^1 free
    if (s + 1 < NSTEP) {
      const int ko = (s + 1) * 64;
#pragma unroll
      for (int j = 0; j < 4; ++j)
        async16(bSrc[j] + ko, (char*)&bT[buf ^ 1][0] + bLds[j]);
      if ((s & 1) == 1) bwn = bitsRow[(s + 1) >> 1];  // next uint4 (2 steps)
    }
    const unsigned dw0 = (s & 1) ? bw.z : bw.x;   // k [s*64, +32)
    const unsigned dw1 = (s & 1) ? bw.w : bw.y;   // k [s*64+32, +32)
#pragma unroll
    for (int kk = 0; kk < 2; ++kk) {
      const unsigned byte = ((kk ? dw1 : dw0) >> (quad * 8)) & 0xFFu;
      union { bf16x8 v; unsigned short u[8]; } a;
#pragma unroll
      for (int j = 0; j < 8; ++j) a.u[j] = (byte >> j) & 1 ? 0x3F80 : 0;
#pragma unroll
      for (int ct = 0; ct < 8; ++ct) {
        bf16x8 bb = *(const bf16x8*)
            &bT[buf][(ct * 16 + l16) * 64 + (((kk * 4 + quad) ^ sw) << 3)];
        acc[ct] = __builtin_amdgcn_mfma_f32_16x16x32_bf16(a.v, bb, acc[ct], 0, 0, 0);
      }
    }
    if (s & 1) bw = bwn;
  }
  float* pp = part + (size_t)split * NN * DIM;
#pragma unroll
  for (int ct = 0; ct < 8; ++ct)
    for (int r = 0; r < 4; ++r)
      pp[(m0 + wave * 16 + quad * 4 + r) * DIM + ct * 16 + l16] = acc[ct][r];
}

// ---------------- K3: fused GRU; agg = (sum of KSPLIT fp32 partials)/deg.
__global__ __launch_bounds__(256) void k3_gru(
    const float* __restrict__ nf, const float* __restrict__ part,
    const int* __restrict__ deg,
    const float* __restrict__ w_ih, const float* __restrict__ w_hh,
    const float* __restrict__ b_ih, const float* __restrict__ b_hh,
    float* __restrict__ out) {
  __shared__ unsigned short aggL[32 * LSTR];
  __shared__ unsigned short nfL[32 * LSTR];
  __shared__ unsigned short wL[128 * LSTR];
  __shared__ float invD[32];
  const int t = threadIdx.x;
  const int m0 = blockIdx.x * 32;
  if (t < 32) {
    const int d = deg[m0 + t];
    invD[t] = 1.0f / (float)(d > 1 ? d : 1);
  }
  __syncthreads();
  const float4* p4 = (const float4*)part;
  const float4* nf4 = (const float4*)nf;
  for (int u = t; u < 1024; u += 256) {   // 32 rows x 32 float4
    const int m = u >> 5;
    const int gi = (m0 + m) * 32 + (u & 31);
    float4 s = p4[gi];
    for (int sp = 1; sp < KSPLIT; ++sp) {
      float4 q = p4[sp * (NN * DIM / 4) + gi];
      s.x += q.x; s.y += q.y; s.z += q.z; s.w += q.w;
    }
    const float iv = invD[m];
    s.x *= iv; s.y *= iv; s.z *= iv; s.w *= iv;
    pack4(s, &aggL[m * LSTR + (u & 31) * 4]);
  }
  for (int u = t; u < 1024; u += 256) {
    const int m = u >> 5;
    pack4(nf4[(m0 + m) * 32 + (u & 31)], &nfL[m * LSTR + (u & 31) * 4]);
  }

  const int lane = t & 63, wave = t >> 6;
  const int quad = lane >> 4, l16 = lane & 15;
  const int rt = wave >> 1;
  const int cb = (wave & 1) * 4;
  const int aOff = (rt * 16 + l16) * LSTR + quad * 8;
  const float4* wih4 = (const float4*)w_ih;
  const float4* whh4 = (const float4*)w_hh;

  float gate[4][4];
  const int order[3] = {0, 2, 1};  // r -> n -> z
  for (int ci = 0; ci < 3; ++ci) {
    const int c = order[ci];
    __syncthreads();
    for (int u = t; u < 4096; u += 256)
      pack4(wih4[c * 4096 + u], &wL[(u >> 5) * LSTR + (u & 31) * 4]);
    __syncthreads();
    f32x4 ai[4];
    {
      bf16x8 a[4];
      for (int kk = 0; kk < 4; ++kk) a[kk] = *(const bf16x8*)&aggL[aOff + kk * 32];
      for (int j = 0; j < 4; ++j) {
        f32x4 acc = (f32x4){0.f, 0.f, 0.f, 0.f};
        const int ct = cb + j;
        for (int kk = 0; kk < 4; ++kk) {
          bf16x8 bz = *(const bf16x8*)&wL[(ct * 16 + l16) * LSTR + kk * 32 + quad * 8];
          acc = __builtin_amdgcn_mfma_f32_16x16x32_bf16(a[kk], bz, acc, 0, 0, 0);
        }
        ai[j] = acc;
      }
    }
    __syncthreads();
    for (int u = t; u < 4096; u += 256)
      pack4(whh4[c * 4096 + u], &wL[(u >> 5) * LSTR + (u & 31) * 4]);
    __syncthreads();
    f32x4 ah[4];
    {
      bf16x8 a[4];
      for (int kk = 0; kk < 4; ++kk) a[kk] = *(const bf16x8*)&nfL[aOff + kk * 32];
      for (int j = 0; j < 4; ++j) {
        f32x4 acc = (f32x4){0.f, 0.f, 0.f, 0.f};
        const int ct = cb + j;
        for (int kk = 0; kk < 4; ++kk) {
          bf16x8 bz = *(const bf16x8*)&wL[(ct * 16 + l16) * LSTR + kk * 32 + quad * 8];
          acc = __builtin_amdgcn_mfma_f32_16x16x32_bf16(a[kk], bz, acc, 0, 0, 0);
        }
        ah[j] = acc;
      }
    }
    for (int j = 0; j < 4; ++j) {
      const int col = (cb + j) * 16 + l16;
      const float bi = b_ih[c * 128 + col];
      const float bh = b_hh[c * 128 + col];
      for (int r = 0; r < 4; ++r) {
        const float gi = ai[j][r] + bi;
        const float gh = ah[j][r] + bh;
        if (c == 0) {
          gate[j][r] = sigmoidf_(gi + gh);
        } else if (c == 2) {
          gate[j][r] = tanhf_(gi + gate[j][r] * gh);
        } else {
          const float z = sigmoidf_(gi + gh);
          const int m = m0 + rt * 16 + quad * 4 + r;
          const float h = nf[m * 128 + col];
          out[m * 128 + col] = (1.0f - z) * gate[j][r] + z * h;
        }
      }
    }
  }
}

extern "C" void kernel_launch(void* const* d_in, const int* in_sizes, int n_in,
                              void* d_out, int out_size, void* d_ws, size_t ws_size,
                              hipStream_t stream) {
  const float* nf   = (const float*)d_in[0];
  const int*   adj  = (const int*)d_in[1];
  const float* wmsg = (const float*)d_in[2];
  const float* bmsg = (const float*)d_in[3];
  const float* wih  = (const float*)d_in[4];
  const float* whh  = (const float*)d_in[5];
  const float* bih  = (const float*)d_in[6];
  const float* bhh  = (const float*)d_in[7];
  float* out = (float*)d_out;

  char* ws = (char*)d_ws;
  unsigned int* bits = (unsigned int*)ws;                   // [8192][256] u32    8 MB
  int* deg = (int*)(ws + (size_t)8 * 1024 * 1024);          // [8192]            32 KB
  unsigned short* msgT =
      (unsigned short*)(ws + (size_t)9 * 1024 * 1024);      // bf16 [128][8192]   2 MB
  float* part = (float*)(ws + (size_t)11 * 1024 * 1024);    // f32 [4][8192][128] 16 MB

  k0_pack<<<1024, 256, 0, stream>>>(adj, bits, deg);
  k1_msg<<<NN / 64, 256, 0, stream>>>(nf, wmsg, bmsg, msgT);
  k2_agg<<<(NN / 64) * KSPLIT, 256, 0, stream>>>(bits, msgT, part);
  k3_gru<<<NN / 32, 256, 0, stream>>>(nf, part, deg, wih, whh, bih, bhh, out);
}